// Round 3
// baseline (55.000 us; speedup 1.0000x reference)
//
#include <hip/hip_runtime.h>
#include <hip/hip_bf16.h>

#define H_DIM 3072
#define W_DIM 3072
#define TW 64          // output tile width (px)
#define TH 16          // output tile height (px)
#define BB_ROWS 38     // max bbox rows: ceil(15*ct + 63*st)+2 <= 38 for theta in [0,20deg)
#define BB_STRIDE 204  // floats per LDS row: max cols 67 * 3ch = 201, padded

// 4B-aligned vector type: tap/segment base addrs are only 4B-aligned.
typedef float f32x4 __attribute__((ext_vector_type(4)));
typedef f32x4 __attribute__((aligned(4))) f32x4u;

__global__ __launch_bounds__(256) void rotation_kernel(
    const float* __restrict__ img,     // (H, W, 3) f32
    const float* __restrict__ fv,      // (1,) f32
    float* __restrict__ out)           // (H, W, 3) f32
{
    __shared__ __attribute__((aligned(16))) float S[BB_ROWS * BB_STRIDE];

    const int tx = threadIdx.x;        // 0..15
    const int ty = threadIdx.y;        // 0..15
    const int C0 = blockIdx.x * TW;
    const int R0 = blockIdx.y * TH;

    const float theta = fv[0] * 20.0f * (3.14159265358979323846f / 180.0f);
    const float ct = cosf(theta);
    const float st = sinf(theta);
    const float o_r = (float)H_DIM / 2.0f + 0.5f;   // 1536.5
    const float o_c = (float)W_DIM / 2.0f + 0.5f;

    // ---- block-uniform bbox of source coords, from the 4 tile corners ----
    const float drA = (float)R0 - o_r, drB = (float)(R0 + TH - 1) - o_r;
    const float dcA = (float)C0 - o_c, dcB = (float)(C0 + TW - 1) - o_c;
    float min_r = 1e30f, max_r = -1e30f, min_c = 1e30f, max_c = -1e30f;
    #pragma unroll
    for (int k = 0; k < 4; ++k) {
        const float dr = (k & 1) ? drB : drA;
        const float dc = (k & 2) ? dcB : dcA;
        const float sr = ct * dr - st * dc + o_r;
        const float sc = st * dr + ct * dc + o_c;
        min_r = fminf(min_r, sr); max_r = fmaxf(max_r, sr);
        min_c = fminf(min_c, sc); max_c = fmaxf(max_c, sc);
    }
    // clamp to image; include the +1 tap row/col (r1/c1) even when coords
    // clamp at the border (r0=floor(clamped max), r1=r0+1 must be staged)
    const int r_lo = min(max((int)floorf(min_r), 0), H_DIM - 1);
    const int c_lo = min(max((int)floorf(min_c), 0), W_DIM - 1);
    const int r_hi = min(min(max((int)floorf(max_r), 0), H_DIM - 1) + 1, H_DIM - 1);
    const int c_hi = min(min(max((int)floorf(max_c), 0), W_DIM - 1) + 1, W_DIM - 1);
    const int nrows = r_hi - r_lo + 1;          // <= 38 (proven for theta<20deg)
    const int nflt  = (c_hi - c_lo + 1) * 3;    // <= 201
    const int nflt4 = nflt >> 2;
    const int rem   = nflt & 3;

    // ---- stage bbox into LDS (coalesced float4 rows) ----
    for (int yy = ty; yy < nrows; yy += 16) {
        const float* src = img + ((size_t)(r_lo + yy) * W_DIM + c_lo) * 3;
        float* dst = S + yy * BB_STRIDE;
        for (int xx = tx; xx < nflt4; xx += 16) {
            const f32x4u v = *(const f32x4u*)(src + xx * 4);
            *(f32x4*)(dst + xx * 4) = v;   // 16B-aligned: stride 204*4B = 51*16B
        }
        if (tx < rem) dst[nflt4 * 4 + tx] = src[nflt4 * 4 + tx];
    }
    __syncthreads();

    // ---- gather from LDS: 4 consecutive pixels per thread ----
    const int r = R0 + ty;
    const float dr = (float)r - o_r;
    float res[12];

    #pragma unroll
    for (int p = 0; p < 4; ++p) {
        const int c = C0 + tx * 4 + p;
        const float dc = (float)c - o_c;

        float src_r = ct * dr - st * dc + o_r;
        float src_c = st * dr + ct * dc + o_c;
        src_r = fminf(fmaxf(src_r, 0.0f), (float)(H_DIM - 1));
        src_c = fminf(fmaxf(src_c, 0.0f), (float)(W_DIM - 1));

        const float r0f = floorf(src_r);
        const float c0f = floorf(src_c);
        const float wr = src_r - r0f;
        const float wc = src_c - c0f;

        const int r0 = (int)r0f;
        const int c0 = (int)c0f;
        const int r1 = min(r0 + 1, H_DIM - 1);
        const int c1 = min(c0 + 1, W_DIM - 1);

        int ly0 = r0 - r_lo, ly1 = r1 - r_lo;
        int lx0 = (c0 - c_lo) * 3, lx1 = (c1 - c_lo) * 3;
        // paranoia clamps (no-op when bbox math holds; keeps LDS access safe)
        ly0 = min(max(ly0, 0), BB_ROWS - 1);
        ly1 = min(max(ly1, 0), BB_ROWS - 1);
        lx0 = min(max(lx0, 0), BB_STRIDE - 3);
        lx1 = min(max(lx1, 0), BB_STRIDE - 3);

        const float* s0 = S + ly0 * BB_STRIDE;
        const float* s1 = S + ly1 * BB_STRIDE;

        #pragma unroll
        for (int ch = 0; ch < 3; ++ch) {
            const float t00 = s0[lx0 + ch];
            const float t01 = s0[lx1 + ch];
            const float t10 = s1[lx0 + ch];
            const float t11 = s1[lx1 + ch];
            const float row0 = t00 + wc * (t01 - t00);
            const float row1 = t10 + wc * (t11 - t10);
            res[p * 3 + ch] = row0 + wr * (row1 - row0);
        }
    }

    // 48 contiguous bytes per thread, 16B-aligned: 3x dwordx4 stores
    float4* op = (float4*)(out + ((size_t)r * W_DIM + C0 + tx * 4) * 3);
    op[0] = make_float4(res[0], res[1], res[2],  res[3]);
    op[1] = make_float4(res[4], res[5], res[6],  res[7]);
    op[2] = make_float4(res[8], res[9], res[10], res[11]);
}

extern "C" void kernel_launch(void* const* d_in, const int* in_sizes, int n_in,
                              void* d_out, int out_size, void* d_ws, size_t ws_size,
                              hipStream_t stream) {
    const float* img = (const float*)d_in[0];
    const float* fv  = (const float*)d_in[1];
    float* out = (float*)d_out;

    dim3 block(16, 16, 1);
    dim3 grid(W_DIM / TW, H_DIM / TH, 1);
    rotation_kernel<<<grid, block, 0, stream>>>(img, fv, out);
}